// Round 2
// baseline (127.549 us; speedup 1.0000x reference)
//
#include <hip/hip_runtime.h>
#include <hip/hip_fp16.h>
#include <hip/hip_bf16.h>
#include <stdint.h>

// EXL3 linear: out = Had128( Had128(x*suh) @ dequant(trellis) ) * svh + bias
// B=8, K=4096, N=14336. Tiles are 16x16, 48 uint16 words per tile.

#define IN_F 4096
#define OUT_F 14336
#define BATCH 8
#define TN_TILES 896     // OUT_F/16
#define NW 48            // trellis words per tile
#define KSLICES 8
#define ITERS 16         // MFMA K-steps per kslice (each = 2 tiles = K:32)
#define RS128 0.08838834764831845f  // 1/sqrt(128)

typedef __attribute__((ext_vector_type(4))) float f32x4;
typedef __attribute__((ext_vector_type(8))) short s16x8;

// All scratch in module memory -> zero dependence on ws_size.
__device__ __hip_bfloat16 g_xh[BATCH * IN_F];   // rotated input, bf16
__device__ float g_y[BATCH * OUT_F];            // f32 accumulator for y
__device__ uint32_t g_flags[2];  // [0]: trellis raw-u16? [1]: floats are f32?

// ---------------------------------------------------------------------------
// Format probes.
//  flag0: trellis transported as raw uint16 (any dword high-half nonzero)
//         vs one-uint16-per-int32 (high halves all zero).
//  flag1: fp16 arrays upcast to f32 (mantissa bits 12..0 all zero on every
//         sampled word -- exact property of fp16->f32) vs 16-bit transport.
__global__ void k_detect(const uint32_t* __restrict__ tr,
                         const uint32_t* __restrict__ xw) {
  int lane = threadIdx.x;
  uint32_t hi = 0;
  for (int i = lane; i < 4096; i += 64) hi |= (tr[i] >> 16);
  uint32_t low13 = 0;
  for (int i = lane; i < 256; i += 64) low13 |= (xw[i] & 0x1FFFu);
  int anyhi = __any(hi != 0);
  int anylow = __any(low13 != 0);
  if (lane == 0) {
    g_flags[0] = anyhi ? 1u : 0u;
    g_flags[1] = anylow ? 0u : 1u;
  }
}

// ---------------------------------------------------------------------------
// Input rotation: g_xh = FWHT128(x * suh) / sqrt(128), bf16 [8][4096].
// Also zeroes g_y (each of the 256 blocks clears 448 floats).
__global__ void k_rot_in(const void* __restrict__ xp,
                         const void* __restrict__ suhp) {
  const int b = blockIdx.x;          // 0..255 = 8 rows * 32 blocks
  const int row = b >> 5, blk = b & 31;
  const int lane = threadIdx.x;      // 0..63
  {
    int base = b * 448;
    #pragma unroll
    for (int k = 0; k < 7; ++k) g_y[base + k * 64 + lane] = 0.f;
  }
  const uint32_t ffmt = g_flags[1];
  const int i0 = blk * 128 + lane;
  float x0, x1, s0, s1;
  if (ffmt) {
    const float* x = (const float*)xp;
    const float* sh = (const float*)suhp;
    x0 = x[row * IN_F + i0];      x1 = x[row * IN_F + i0 + 64];
    s0 = sh[i0];                  s1 = sh[i0 + 64];
  } else {
    const __hip_bfloat16* x = (const __hip_bfloat16*)xp;
    const __hip_bfloat16* sh = (const __hip_bfloat16*)suhp;
    x0 = __bfloat162float(x[row * IN_F + i0]);
    x1 = __bfloat162float(x[row * IN_F + i0 + 64]);
    s0 = __bfloat162float(sh[i0]);
    s1 = __bfloat162float(sh[i0 + 64]);
  }
  float v0 = x0 * s0 * RS128;
  float v1 = x1 * s1 * RS128;
  { float a = v0 + v1, s = v0 - v1; v0 = a; v1 = s; }  // distance-64 stage
  #pragma unroll
  for (int d = 32; d >= 1; d >>= 1) {
    float w0 = __shfl_xor(v0, d);
    float w1 = __shfl_xor(v1, d);
    if (lane & d) { v0 = w0 - v0; v1 = w1 - v1; }
    else          { v0 = v0 + w0; v1 = v1 + w1; }
  }
  g_xh[row * IN_F + i0]      = __float2bfloat16(v0);
  g_xh[row * IN_F + i0 + 64] = __float2bfloat16(v1);
}

// ---------------------------------------------------------------------------
// Main kernel: trellis decode directly into MFMA B-fragment layout + GEMM.
// Grid (224, 8): blockIdx.x = group of 4 tile-columns (one per wave),
// blockIdx.y = K-slice (512 k each). atomicAdd partial sums into g_y.
//
// B-fragment (16x16x32 bf16): lane holds B[k=(lane>>4)*8+j][n=lane&15].
// Weight (r,c) has bit offset 48r+3c, so for a fixed lane all 8 weights
// share shift sh = 16-((3c)&15) and hit words w0 + 3j.
__global__ __launch_bounds__(256) void k_main(const uint32_t* __restrict__ tr) {
  __shared__ uint32_t comb[2][8][NW];  // double-buffered windows, 8 tiles
  const int t = threadIdx.x;
  const int lane = t & 63;
  const int wv = t >> 6;               // wave 0..3 -> tile column
  const int bx = blockIdx.x;
  const int ks = blockIdx.y;
  const uint32_t fmt = g_flags[0];     // uniform
  const uint16_t* __restrict__ tr16 = (const uint16_t*)tr;

  const int q   = lane >> 4;           // 0..3: k-octet
  const int cc  = lane & 15;           // column within tile / batch row m
  const int r0  = (q & 1) << 3;        // row base within 16-tile
  const int par = q >> 1;              // which tile of the K=32 pair
  const int w0  = 3 * r0 + ((3 * cc) >> 4);
  const uint32_t sh = 16u - (uint32_t)((3 * cc) & 15);  // 1..16

  f32x4 acc = {0.f, 0.f, 0.f, 0.f};

  auto stage = [&](int it, int buf) {
    const int tk0 = ks * 32 + it * 2;
    #pragma unroll
    for (int rep = 0; rep < 2; ++rep) {
      int idx = t + rep * 256;
      if (idx < 8 * NW) {
        int tile = idx / NW;
        int w = idx - tile * NW;
        int wvs = tile >> 1;
        int p2 = tile & 1;
        long gb = ((long)(tk0 + p2) * TN_TILES + (bx * 4 + wvs)) * NW;
        int w1 = (w + 1 == NW) ? 0 : (w + 1);  // tail-biting wrap
        uint32_t hiw, low;
        if (fmt) { hiw = tr16[gb + w]; low = tr16[gb + w1]; }
        else     { hiw = tr[gb + w];   low = tr[gb + w1]; }
        comb[buf][tile][w] = (hiw << 16) | low;
      }
    }
  };

  stage(0, 0);
  __syncthreads();

  for (int it = 0; it < ITERS; ++it) {
    const int cur = it & 1;
    if (it + 1 < ITERS) stage(it + 1, cur ^ 1);  // prefetch next pair

    const uint32_t* cb = &comb[cur][wv * 2 + par][0];
    float val[8];
    #pragma unroll
    for (int j = 0; j < 8; ++j) {
      uint32_t cw = cb[w0 + 3 * j];
      uint32_t st = (cw >> sh) & 0xFFFFu;
      // z = st*89226354 + 64248484 (mod 2^32); 89226354 = 1361*65536+31858
      uint32_t zz = __umul24(st, 31858u) + 64248484u +
                    (__umul24(st, 1361u) << 16);
      zz &= 0x8FFF8FFFu;
      float flo = __half2float(__ushort_as_half((unsigned short)(zz & 0xFFFFu)));
      float fhi = __half2float(__ushort_as_half((unsigned short)(zz >> 16)));
      val[j] = flo + fhi;
    }
    // RNE pack f32 -> bf16 pairs
    uint32_t pk[4];
    #pragma unroll
    for (int j2 = 0; j2 < 4; ++j2) {
      uint32_t u0 = __float_as_uint(val[2 * j2]);
      uint32_t u1 = __float_as_uint(val[2 * j2 + 1]);
      u0 += 0x7FFFu + ((u0 >> 16) & 1u);
      u1 += 0x7FFFu + ((u1 >> 16) & 1u);
      pk[j2] = (u0 >> 16) | (u1 & 0xFFFF0000u);
    }
    union { uint32_t u[4]; s16x8 v; } bu;
    bu.u[0] = pk[0]; bu.u[1] = pk[1]; bu.u[2] = pk[2]; bu.u[3] = pk[3];

    // A fragment: A[m=cc][k = tk0*16 + q*8 + j]; batch rows 8..15 are zero.
    const int tk0 = ks * 32 + it * 2;
    s16x8 afrag = {0, 0, 0, 0, 0, 0, 0, 0};
    if (cc < 8)
      afrag = *(const s16x8*)(g_xh + cc * IN_F + tk0 * 16 + q * 8);

    acc = __builtin_amdgcn_mfma_f32_16x16x32_bf16(afrag, bu.v, acc, 0, 0, 0);
    __syncthreads();
  }

  // C layout: col = lane&15, row = (lane>>4)*4 + reg; rows 0..7 are real.
  if (q < 2) {
    const int n = (bx * 4 + wv) * 16 + cc;
    #pragma unroll
    for (int rg = 0; rg < 4; ++rg) {
      int row = q * 4 + rg;
      atomicAdd(&g_y[row * OUT_F + n], acc[rg]);
    }
  }
}

// ---------------------------------------------------------------------------
// Output rotation: out = FWHT128(g_y)/sqrt(128)*svh + bias.
__global__ void k_rot_out(const void* __restrict__ svhp,
                          const void* __restrict__ biasp,
                          void* __restrict__ outp) {
  const int nblk = blockIdx.x;   // 0..111
  const int row = blockIdx.y;    // 0..7
  const int lane = threadIdx.x;  // 0..63
  const uint32_t ffmt = g_flags[1];
  const int n0 = nblk * 128 + lane;
  float v0 = g_y[row * OUT_F + n0] * RS128;
  float v1 = g_y[row * OUT_F + n0 + 64] * RS128;
  { float a = v0 + v1, s = v0 - v1; v0 = a; v1 = s; }
  #pragma unroll
  for (int d = 32; d >= 1; d >>= 1) {
    float w0 = __shfl_xor(v0, d);
    float w1 = __shfl_xor(v1, d);
    if (lane & d) { v0 = w0 - v0; v1 = w1 - v1; }
    else          { v0 = v0 + w0; v1 = v1 + w1; }
  }
  if (ffmt) {
    const float* svh = (const float*)svhp;
    const float* bias = (const float*)biasp;
    float* out = (float*)outp;
    out[(long)row * OUT_F + n0]      = v0 * svh[n0] + bias[n0];
    out[(long)row * OUT_F + n0 + 64] = v1 * svh[n0 + 64] + bias[n0 + 64];
  } else {
    const __hip_bfloat16* svh = (const __hip_bfloat16*)svhp;
    const __hip_bfloat16* bias = (const __hip_bfloat16*)biasp;
    __hip_bfloat16* out = (__hip_bfloat16*)outp;
    out[(long)row * OUT_F + n0] = __float2bfloat16(
        v0 * __bfloat162float(svh[n0]) + __bfloat162float(bias[n0]));
    out[(long)row * OUT_F + n0 + 64] = __float2bfloat16(
        v1 * __bfloat162float(svh[n0 + 64]) + __bfloat162float(bias[n0 + 64]));
  }
}

// ---------------------------------------------------------------------------
extern "C" void kernel_launch(void* const* d_in, const int* in_sizes, int n_in,
                              void* d_out, int out_size, void* d_ws,
                              size_t ws_size, hipStream_t stream) {
  const void*     x    = d_in[0];
  const uint32_t* tr   = (const uint32_t*)d_in[1];
  const void*     suh  = d_in[2];
  const void*     svh  = d_in[3];
  const void*     bias = d_in[4];

  k_detect<<<1, 64, 0, stream>>>(tr, (const uint32_t*)x);
  k_rot_in<<<256, 64, 0, stream>>>(x, suh);
  k_main<<<dim3(TN_TILES / 4, KSLICES), 256, 0, stream>>>(tr);
  k_rot_out<<<dim3(OUT_F / 128, BATCH), 64, 0, stream>>>(svh, bias, d_out);
}

// Round 3
// 108.009 us; speedup vs baseline: 1.1809x; 1.1809x over previous
//
#include <hip/hip_runtime.h>
#include <hip/hip_fp16.h>
#include <hip/hip_bf16.h>
#include <stdint.h>

// EXL3 linear: out = Had128( Had128(x*suh) @ dequant(trellis) ) * svh + bias
// B=8, K=4096, N=14336. Tiles are 16x16, 48 uint16 words per tile.

#define IN_F 4096
#define OUT_F 14336
#define BATCH 8
#define TN_TILES 896     // OUT_F/16
#define KSLICES 8
#define ITERS 16         // MFMA K-steps per kslice (each = 2 k-tiles = K:32)
#define RS128 0.08838834764831845f  // 1/sqrt(128)

typedef __attribute__((ext_vector_type(4))) float f32x4;
typedef __attribute__((ext_vector_type(8))) _Float16 f16x8;

// All scratch in module memory -> zero dependence on ws_size.
__device__ _Float16 g_xh[BATCH * IN_F];   // rotated input, f16
__device__ float g_y[BATCH * OUT_F];      // f32 accumulator for y
__device__ uint32_t g_flags[2];  // [0]: trellis raw-u16? [1]: floats are f32?

// ---------------------------------------------------------------------------
// Format probes (512 trellis dwords, 256 x dwords — ample confidence).
__global__ void k_detect(const uint32_t* __restrict__ tr,
                         const uint32_t* __restrict__ xw) {
  int lane = threadIdx.x;
  uint32_t hi = 0;
  #pragma unroll
  for (int k = 0; k < 8; ++k) hi |= (tr[k * 64 + lane] >> 16);
  uint32_t low13 = 0;
  #pragma unroll
  for (int k = 0; k < 4; ++k) low13 |= (xw[k * 64 + lane] & 0x1FFFu);
  int anyhi = __any(hi != 0);
  int anylow = __any(low13 != 0);
  if (lane == 0) {
    g_flags[0] = anyhi ? 1u : 0u;   // raw u16 packing
    g_flags[1] = anylow ? 0u : 1u;  // 1 => fp16 was upcast to f32
  }
}

// ---------------------------------------------------------------------------
// Input rotation: g_xh = FWHT128(x * suh) / sqrt(128), f16 [8][4096].
// Also zeroes g_y (each of the 256 blocks clears 448 floats).
__global__ void k_rot_in(const void* __restrict__ xp,
                         const void* __restrict__ suhp) {
  const int b = blockIdx.x;          // 0..255 = 8 rows * 32 blocks
  const int row = b >> 5, blk = b & 31;
  const int lane = threadIdx.x;      // 0..63
  {
    int base = b * 448;
    #pragma unroll
    for (int k = 0; k < 7; ++k) g_y[base + k * 64 + lane] = 0.f;
  }
  const uint32_t ffmt = g_flags[1];
  const int i0 = blk * 128 + lane;
  float x0, x1, s0, s1;
  if (ffmt) {
    const float* x = (const float*)xp;
    const float* sh = (const float*)suhp;
    x0 = x[row * IN_F + i0];      x1 = x[row * IN_F + i0 + 64];
    s0 = sh[i0];                  s1 = sh[i0 + 64];
  } else {
    const __hip_bfloat16* x = (const __hip_bfloat16*)xp;
    const __hip_bfloat16* sh = (const __hip_bfloat16*)suhp;
    x0 = __bfloat162float(x[row * IN_F + i0]);
    x1 = __bfloat162float(x[row * IN_F + i0 + 64]);
    s0 = __bfloat162float(sh[i0]);
    s1 = __bfloat162float(sh[i0 + 64]);
  }
  float v0 = x0 * s0 * RS128;
  float v1 = x1 * s1 * RS128;
  { float a = v0 + v1, s = v0 - v1; v0 = a; v1 = s; }  // distance-64 stage
  #pragma unroll
  for (int d = 32; d >= 1; d >>= 1) {
    float w0 = __shfl_xor(v0, d);
    float w1 = __shfl_xor(v1, d);
    if (lane & d) { v0 = w0 - v0; v1 = w1 - v1; }
    else          { v0 = v0 + w0; v1 = v1 + w1; }
  }
  g_xh[row * IN_F + i0]      = (_Float16)v0;
  g_xh[row * IN_F + i0 + 64] = (_Float16)v1;
}

// ---------------------------------------------------------------------------
// Main kernel: wave-autonomous trellis decode + f16 MFMA. NO __syncthreads.
// Grid (224, 8): wave wv of block bx owns tile-column tn = bx*4+wv for
// kslice blockIdx.y (32 k-tiles). Per iteration a wave stages its own two
// 96-B tiles into a private LDS slice (same-wave DS ops are in-order, so
// ds_write -> ds_read needs no barrier), decodes 16 weights/lane directly
// into the f16 B-fragment, and issues one 16x16x32 f16 MFMA.
//
// B-frag: lane holds B[k=(lane>>4)*8+j][n=lane&15], j ascending in the
// packed f16x8. Weight (a=k&15, b=n&15) has bit offset 48a+3b -> all 8
// weights of a lane share shift r=(3b)&15 and hit words w0+3j.
__global__ __launch_bounds__(256) void k_main(const uint32_t* __restrict__ tr) {
  __shared__ uint32_t comb[4][2][96];  // [wave][buf][2 tiles x 48 words]
  const int t = threadIdx.x;
  const int lane = t & 63;
  const int wv = t >> 6;
  const int tn = blockIdx.x * 4 + wv;
  const int ks = blockIdx.y;
  const uint32_t fmt = g_flags[0];

  // staging role: lanes (tsel*32 + m), m<24 each produce comb[2m], comb[2m+1]
  const int m = lane & 31;
  const int mm = (m < 24) ? m : 0;   // keep inactive lanes in-bounds
  const int tsel = lane >> 5;        // which of the 2 k-adjacent tiles
  const int src = (m == 23) ? (lane - 23) : (lane + 1);  // tail-bite wrap

  // decode role
  const int q = lane >> 4;           // k-octet 0..3
  const int cc = lane & 15;          // column b within tile
  const int par = q >> 1;            // tile of the K=32 pair
  const int w0 = 3 * ((q & 1) << 3) + ((3 * cc) >> 4);
  const uint32_t shr = 16u - (uint32_t)((3 * cc) & 15);  // 1..16

  auto gload = [&](int it) -> uint32_t {
    const int tk = ks * 32 + it * 2 + tsel;
    const long tb = (long)tk * TN_TILES + tn;
    if (fmt) {                        // raw u16: 24 dwords per tile
      return tr[tb * 24 + mm];
    } else {                          // one u16 per int32: 48 dwords per tile
      uint32_t u0 = tr[tb * 48 + 2 * mm];
      uint32_t u1 = tr[tb * 48 + 2 * mm + 1];
      return u0 | (u1 << 16);
    }
  };

  f32x4 acc = {0.f, 0.f, 0.f, 0.f};
  uint32_t X = gload(0);

  #pragma unroll 4
  for (int it = 0; it < ITERS; ++it) {
    const int buf = it & 1;
    // build comb windows: X = u[2m] | (u[2m+1]<<16)
    uint32_t Y = __shfl(X, src);                         // next dword (wrapped)
    uint32_t c0 = (X >> 16) | (X << 16);                 // (u[2m]<<16)|u[2m+1]
    uint32_t c1 = __builtin_amdgcn_perm(X, Y, 0x07060100u); // (u[2m+1]<<16)|u[2m+2]
    if (m < 24) {
      uint32_t* cw = &comb[wv][buf][tsel * 48 + 2 * m];
      cw[0] = c0; cw[1] = c1;
    }
    uint32_t Xn = (it + 1 < ITERS) ? gload(it + 1) : 0u; // prefetch

    const uint32_t* cb = &comb[wv][buf][par * 48 + w0];
    union { __half2 h[4]; f16x8 v; } bfrag;
    #pragma unroll
    for (int g = 0; g < 4; ++g) {
      uint32_t cw0 = cb[6 * g];
      uint32_t cw1 = cb[6 * g + 3];
      uint32_t st0 = (cw0 >> shr) & 0xFFFFu;
      uint32_t st1 = (cw1 >> shr) & 0xFFFFu;
      // z = st*89226354 + 64248484; 89226354 = 1361*65536 + 31858
      uint32_t z0 = __umul24(st0, 31858u) + 64248484u + (__umul24(st0, 1361u) << 16);
      uint32_t z1 = __umul24(st1, 31858u) + 64248484u + (__umul24(st1, 1361u) << 16);
      z0 &= 0x8FFF8FFFu; z1 &= 0x8FFF8FFFu;
      uint32_t lo = __builtin_amdgcn_perm(z1, z0, 0x05040100u); // (z0.lo, z1.lo)
      uint32_t hi = __builtin_amdgcn_perm(z1, z0, 0x07060302u); // (z0.hi, z1.hi)
      __half2 ha = *(__half2*)&lo;
      __half2 hb = *(__half2*)&hi;
      bfrag.h[g] = __hadd2(ha, hb);   // two finished weights, packed f16
    }

    // A fragment: A[m=cc][k]; batch rows 8..15 are zero.
    f16x8 afrag = {0, 0, 0, 0, 0, 0, 0, 0};
    if (cc < 8)
      afrag = *(const f16x8*)(g_xh + cc * IN_F + ks * 512 + it * 32 + q * 8);

    acc = __builtin_amdgcn_mfma_f32_16x16x32_f16(afrag, bfrag.v, acc, 0, 0, 0);
    X = Xn;
  }

  // C layout: col = lane&15, row = (lane>>4)*4 + reg; rows 0..7 are real.
  if (q < 2) {
    const int n = tn * 16 + cc;
    #pragma unroll
    for (int rg = 0; rg < 4; ++rg)
      atomicAdd(&g_y[(q * 4 + rg) * OUT_F + n], acc[rg]);
  }
}

// ---------------------------------------------------------------------------
// Output rotation: out = FWHT128(g_y)/sqrt(128)*svh + bias.
__global__ void k_rot_out(const void* __restrict__ svhp,
                          const void* __restrict__ biasp,
                          void* __restrict__ outp) {
  const int nblk = blockIdx.x;   // 0..111
  const int row = blockIdx.y;    // 0..7
  const int lane = threadIdx.x;  // 0..63
  const uint32_t ffmt = g_flags[1];
  const int n0 = nblk * 128 + lane;
  float v0 = g_y[row * OUT_F + n0] * RS128;
  float v1 = g_y[row * OUT_F + n0 + 64] * RS128;
  { float a = v0 + v1, s = v0 - v1; v0 = a; v1 = s; }
  #pragma unroll
  for (int d = 32; d >= 1; d >>= 1) {
    float w0 = __shfl_xor(v0, d);
    float w1 = __shfl_xor(v1, d);
    if (lane & d) { v0 = w0 - v0; v1 = w1 - v1; }
    else          { v0 = v0 + w0; v1 = v1 + w1; }
  }
  if (ffmt) {
    const float* svh = (const float*)svhp;
    const float* bias = (const float*)biasp;
    float* out = (float*)outp;
    out[(long)row * OUT_F + n0]      = v0 * svh[n0] + bias[n0];
    out[(long)row * OUT_F + n0 + 64] = v1 * svh[n0 + 64] + bias[n0 + 64];
  } else {
    const __hip_bfloat16* svh = (const __hip_bfloat16*)svhp;
    const __hip_bfloat16* bias = (const __hip_bfloat16*)biasp;
    __hip_bfloat16* out = (__hip_bfloat16*)outp;
    out[(long)row * OUT_F + n0] = __float2bfloat16(
        v0 * __bfloat162float(svh[n0]) + __bfloat162float(bias[n0]));
    out[(long)row * OUT_F + n0 + 64] = __float2bfloat16(
        v1 * __bfloat162float(svh[n0 + 64]) + __bfloat162float(bias[n0 + 64]));
  }
}

// ---------------------------------------------------------------------------
extern "C" void kernel_launch(void* const* d_in, const int* in_sizes, int n_in,
                              void* d_out, int out_size, void* d_ws,
                              size_t ws_size, hipStream_t stream) {
  const void*     x    = d_in[0];
  const uint32_t* tr   = (const uint32_t*)d_in[1];
  const void*     suh  = d_in[2];
  const void*     svh  = d_in[3];
  const void*     bias = d_in[4];

  k_detect<<<1, 64, 0, stream>>>(tr, (const uint32_t*)x);
  k_rot_in<<<256, 64, 0, stream>>>(x, suh);
  k_main<<<dim3(TN_TILES / 4, KSLICES), 256, 0, stream>>>(tr);
  k_rot_out<<<dim3(OUT_F / 128, BATCH), 64, 0, stream>>>(svh, bias, d_out);
}

// Round 4
// 105.950 us; speedup vs baseline: 1.2039x; 1.0194x over previous
//
#include <hip/hip_runtime.h>
#include <hip/hip_fp16.h>
#include <hip/hip_bf16.h>
#include <stdint.h>

// EXL3 linear: out = Had128( Had128(x*suh) @ dequant(trellis) ) * svh + bias
// B=8, K=4096, N=14336. Tiles are 16x16, 48 uint16 words per tile.

#define IN_F 4096
#define OUT_F 14336
#define BATCH 8
#define TN_TILES 896     // OUT_F/16
#define KSLICES 8
#define ITERS 16         // MFMA K-steps per kslice (each = 2 k-tiles = K:32)
#define RS128 0.08838834764831845f  // 1/sqrt(128)

typedef __attribute__((ext_vector_type(4))) float f32x4;
typedef __attribute__((ext_vector_type(8))) _Float16 f16x8;

// All scratch in module memory -> zero dependence on ws_size.
__device__ _Float16 g_xh[BATCH * IN_F];   // rotated input, f16
__device__ float g_y[BATCH * OUT_F];      // f32 accumulator for y
__device__ uint32_t g_flags[2];  // [0]: trellis raw-u16? [1]: floats are f32?

// ---------------------------------------------------------------------------
// Format probes.
__global__ void k_detect(const uint32_t* __restrict__ tr,
                         const uint32_t* __restrict__ xw) {
  int lane = threadIdx.x;
  uint32_t hi = 0;
  #pragma unroll
  for (int k = 0; k < 8; ++k) hi |= (tr[k * 64 + lane] >> 16);
  uint32_t low13 = 0;
  #pragma unroll
  for (int k = 0; k < 4; ++k) low13 |= (xw[k * 64 + lane] & 0x1FFFu);
  int anyhi = __any(hi != 0);
  int anylow = __any(low13 != 0);
  if (lane == 0) {
    g_flags[0] = anyhi ? 1u : 0u;   // raw u16 packing
    g_flags[1] = anylow ? 0u : 1u;  // 1 => fp16 was upcast to f32
  }
}

// ---------------------------------------------------------------------------
// Input rotation: g_xh = FWHT128(x * suh) / sqrt(128), f16 [8][4096].
// Also zeroes g_y (each of the 256 blocks clears 448 floats).
__global__ void k_rot_in(const void* __restrict__ xp,
                         const void* __restrict__ suhp) {
  const int b = blockIdx.x;          // 0..255 = 8 rows * 32 blocks
  const int row = b >> 5, blk = b & 31;
  const int lane = threadIdx.x;      // 0..63
  {
    int base = b * 448;
    #pragma unroll
    for (int k = 0; k < 7; ++k) g_y[base + k * 64 + lane] = 0.f;
  }
  const uint32_t ffmt = g_flags[1];
  const int i0 = blk * 128 + lane;
  float x0, x1, s0, s1;
  if (ffmt) {
    const float* x = (const float*)xp;
    const float* sh = (const float*)suhp;
    x0 = x[row * IN_F + i0];      x1 = x[row * IN_F + i0 + 64];
    s0 = sh[i0];                  s1 = sh[i0 + 64];
  } else {
    const __hip_bfloat16* x = (const __hip_bfloat16*)xp;
    const __hip_bfloat16* sh = (const __hip_bfloat16*)suhp;
    x0 = __bfloat162float(x[row * IN_F + i0]);
    x1 = __bfloat162float(x[row * IN_F + i0 + 64]);
    s0 = __bfloat162float(sh[i0]);
    s1 = __bfloat162float(sh[i0 + 64]);
  }
  float v0 = x0 * s0 * RS128;
  float v1 = x1 * s1 * RS128;
  { float a = v0 + v1, s = v0 - v1; v0 = a; v1 = s; }  // distance-64 stage
  #pragma unroll
  for (int d = 32; d >= 1; d >>= 1) {
    float w0 = __shfl_xor(v0, d);
    float w1 = __shfl_xor(v1, d);
    if (lane & d) { v0 = w0 - v0; v1 = w1 - v1; }
    else          { v0 = v0 + w0; v1 = v1 + w1; }
  }
  g_xh[row * IN_F + i0]      = (_Float16)v0;
  g_xh[row * IN_F + i0 + 64] = (_Float16)v1;
}

// ---------------------------------------------------------------------------
// Main kernel. Grid (224, 8): wave wv of block bx owns tile-column
// tn = bx*4+wv for kslice ks (32 k-tiles). Structure:
//   PROLOGUE: each lane bulk-loads half a tile (48 B) for all 32 tiles
//   (3 dwordx4 x ... lane l -> tile l>>1, half l&1), builds comb windows
//   c[w] = u[w]<<16 | u[w+1] in registers, writes them to a wave-private
//   LDS slice (6 ds_write_b128). Wave-private => NO barriers anywhere.
//   K-LOOP: pure LDS+VALU+MFMA. Weight pair (j,j+1) = one ds_read2_b32
//   (words w0+6g, w0+6g+3); extraction = one v_bfe; 3INST LCG via u24 muls;
//   f16 pack via v_perm + pk_add; one 16x16x32 f16 MFMA per iter.
// B-frag: lane holds B[k=(lane>>4)*8+j][n=lane&15]. Weight (u=k&15, c=n&15)
// has bit offset 48u+3c -> word w0+3j, shift 16-((3c)&15), w0=3*r0+((3c)>>4).
__global__ __launch_bounds__(256) void k_main(const uint32_t* __restrict__ tr) {
  __shared__ uint32_t cwin[4][32][48];  // [wave][tile (=2*it+par)][comb words]
  const int t = threadIdx.x;
  const int lane = t & 63;
  const int wv = t >> 6;
  const int tn = blockIdx.x * 4 + wv;
  const int ks = blockIdx.y;
  const uint32_t fmt = g_flags[0];

  // ---- prologue ----
  const int tile = lane >> 1;   // 0..31
  const int h = lane & 1;       // which 24-u16 half of the tile
  uint32_t d[12];
  if (fmt) {
    const uint4* gp = (const uint4*)(tr +
        ((long)(ks * 32 + tile) * TN_TILES + tn) * 24 + h * 12);
    uint4 a0 = gp[0], a1 = gp[1], a2 = gp[2];
    d[0] = a0.x; d[1] = a0.y; d[2]  = a0.z; d[3]  = a0.w;
    d[4] = a1.x; d[5] = a1.y; d[6]  = a1.z; d[7]  = a1.w;
    d[8] = a2.x; d[9] = a2.y; d[10] = a2.z; d[11] = a2.w;
  } else {
    const uint4* gp = (const uint4*)(tr +
        ((long)(ks * 32 + tile) * TN_TILES + tn) * 48 + h * 24);
    uint4 b0 = gp[0], b1 = gp[1], b2 = gp[2];
    uint4 b3 = gp[3], b4 = gp[4], b5 = gp[5];
    // pack one u16 per dword -> two per dword (little-endian)
    d[0]  = __builtin_amdgcn_perm(b0.y, b0.x, 0x05040100u);
    d[1]  = __builtin_amdgcn_perm(b0.w, b0.z, 0x05040100u);
    d[2]  = __builtin_amdgcn_perm(b1.y, b1.x, 0x05040100u);
    d[3]  = __builtin_amdgcn_perm(b1.w, b1.z, 0x05040100u);
    d[4]  = __builtin_amdgcn_perm(b2.y, b2.x, 0x05040100u);
    d[5]  = __builtin_amdgcn_perm(b2.w, b2.z, 0x05040100u);
    d[6]  = __builtin_amdgcn_perm(b3.y, b3.x, 0x05040100u);
    d[7]  = __builtin_amdgcn_perm(b3.w, b3.z, 0x05040100u);
    d[8]  = __builtin_amdgcn_perm(b4.y, b4.x, 0x05040100u);
    d[9]  = __builtin_amdgcn_perm(b4.w, b4.z, 0x05040100u);
    d[10] = __builtin_amdgcn_perm(b5.y, b5.x, 0x05040100u);
    d[11] = __builtin_amdgcn_perm(b5.w, b5.z, 0x05040100u);
  }
  // partner's first dword supplies u[24] (h=0) / wrap u[0] (h=1)
  uint32_t dnext = __shfl(d[0], lane ^ 1, 64);
  uint32_t c[24];
  #pragma unroll
  for (int m = 0; m < 12; ++m) {
    uint32_t nx = (m < 11) ? d[m + 1] : dnext;
    c[2 * m]     = (d[m] >> 16) | (d[m] << 16);             // u[2m]<<16|u[2m+1]
    c[2 * m + 1] = __builtin_amdgcn_perm(d[m], nx, 0x07060100u); // u[2m+1]<<16|u[2m+2]
  }
  {
    uint32_t* wp = &cwin[wv][tile][h * 24];
    #pragma unroll
    for (int k = 0; k < 6; ++k)
      *(uint4*)(wp + 4 * k) = *(const uint4*)(c + 4 * k);
  }
  // no barrier: each wave reads only its own slice (same-wave DS in-order)

  // ---- K-loop ----
  const int q = lane >> 4;           // k-octet 0..3
  const int cc = lane & 15;          // column within tile
  const int par = q >> 1;            // which tile of the K=32 pair
  const int w0 = 3 * ((q & 1) << 3) + ((3 * cc) >> 4);
  const uint32_t shr = 16u - (uint32_t)((3 * cc) & 15);  // 1..16
  const uint32_t* myc = &cwin[wv][par][w0];

  f32x4 acc = {0.f, 0.f, 0.f, 0.f};

  #pragma unroll 4
  for (int it = 0; it < ITERS; ++it) {
    const uint32_t* cb = myc + it * 96;  // advance 2 tiles per iter
    union { __half2 h2[4]; f16x8 v; } bfrag;
    #pragma unroll
    for (int g = 0; g < 4; ++g) {
      uint32_t cw0 = cb[6 * g];        // -> ds_read2_b32 (offsets 6g, 6g+3)
      uint32_t cw1 = cb[6 * g + 3];
      uint32_t st0 = (cw0 >> shr) & 0xFFFFu;   // v_bfe
      uint32_t st1 = (cw1 >> shr) & 0xFFFFu;
      // z = st*89226354 + 64248484; 89226354 = 1361*65536 + 31858
      uint32_t z0 = __umul24(st0, 31858u) + 64248484u + (__umul24(st0, 1361u) << 16);
      uint32_t z1 = __umul24(st1, 31858u) + 64248484u + (__umul24(st1, 1361u) << 16);
      z0 &= 0x8FFF8FFFu; z1 &= 0x8FFF8FFFu;
      uint32_t lo = __builtin_amdgcn_perm(z1, z0, 0x05040100u); // (z0.lo, z1.lo)
      uint32_t hi = __builtin_amdgcn_perm(z1, z0, 0x07060302u); // (z0.hi, z1.hi)
      __half2 ha = *(__half2*)&lo;
      __half2 hb = *(__half2*)&hi;
      bfrag.h2[g] = __hadd2(ha, hb);   // two finished weights, packed f16
    }

    // A fragment: A[m=cc][k]; batch rows 8..15 are zero.
    f16x8 afrag = {0, 0, 0, 0, 0, 0, 0, 0};
    if (cc < 8)
      afrag = *(const f16x8*)(g_xh + cc * IN_F + ks * 512 + it * 32 + q * 8);

    acc = __builtin_amdgcn_mfma_f32_16x16x32_f16(afrag, bfrag.v, acc, 0, 0, 0);
  }

  // C layout: col = lane&15, row = (lane>>4)*4 + reg; rows 0..7 are real.
  if (q < 2) {
    const int n = tn * 16 + cc;
    #pragma unroll
    for (int rg = 0; rg < 4; ++rg)
      atomicAdd(&g_y[(q * 4 + rg) * OUT_F + n], acc[rg]);
  }
}

// ---------------------------------------------------------------------------
// Output rotation: out = FWHT128(g_y)/sqrt(128)*svh + bias.
__global__ void k_rot_out(const void* __restrict__ svhp,
                          const void* __restrict__ biasp,
                          void* __restrict__ outp) {
  const int nblk = blockIdx.x;   // 0..111
  const int row = blockIdx.y;    // 0..7
  const int lane = threadIdx.x;  // 0..63
  const uint32_t ffmt = g_flags[1];
  const int n0 = nblk * 128 + lane;
  float v0 = g_y[row * OUT_F + n0] * RS128;
  float v1 = g_y[row * OUT_F + n0 + 64] * RS128;
  { float a = v0 + v1, s = v0 - v1; v0 = a; v1 = s; }
  #pragma unroll
  for (int d = 32; d >= 1; d >>= 1) {
    float w0 = __shfl_xor(v0, d);
    float w1 = __shfl_xor(v1, d);
    if (lane & d) { v0 = w0 - v0; v1 = w1 - v1; }
    else          { v0 = v0 + w0; v1 = v1 + w1; }
  }
  if (ffmt) {
    const float* svh = (const float*)svhp;
    const float* bias = (const float*)biasp;
    float* out = (float*)outp;
    out[(long)row * OUT_F + n0]      = v0 * svh[n0] + bias[n0];
    out[(long)row * OUT_F + n0 + 64] = v1 * svh[n0 + 64] + bias[n0 + 64];
  } else {
    const __hip_bfloat16* svh = (const __hip_bfloat16*)svhp;
    const __hip_bfloat16* bias = (const __hip_bfloat16*)biasp;
    __hip_bfloat16* out = (__hip_bfloat16*)outp;
    out[(long)row * OUT_F + n0] = __float2bfloat16(
        v0 * __bfloat162float(svh[n0]) + __bfloat162float(bias[n0]));
    out[(long)row * OUT_F + n0 + 64] = __float2bfloat16(
        v1 * __bfloat162float(svh[n0 + 64]) + __bfloat162float(bias[n0 + 64]));
  }
}

// ---------------------------------------------------------------------------
extern "C" void kernel_launch(void* const* d_in, const int* in_sizes, int n_in,
                              void* d_out, int out_size, void* d_ws,
                              size_t ws_size, hipStream_t stream) {
  const void*     x    = d_in[0];
  const uint32_t* tr   = (const uint32_t*)d_in[1];
  const void*     suh  = d_in[2];
  const void*     svh  = d_in[3];
  const void*     bias = d_in[4];

  k_detect<<<1, 64, 0, stream>>>(tr, (const uint32_t*)x);
  k_rot_in<<<256, 64, 0, stream>>>(x, suh);
  k_main<<<dim3(TN_TILES / 4, KSLICES), 256, 0, stream>>>(tr);
  k_rot_out<<<dim3(OUT_F / 128, BATCH), 64, 0, stream>>>(svh, bias, d_out);
}

// Round 6
// 104.905 us; speedup vs baseline: 1.2159x; 1.0100x over previous
//
#include <hip/hip_runtime.h>
#include <hip/hip_fp16.h>
#include <hip/hip_bf16.h>
#include <stdint.h>

// EXL3 linear: out = Had128( Had128(x*suh) @ dequant(trellis) ) * svh + bias
// B=8, K=4096, N=14336. Tiles are 16x16, 48 uint16 words per tile.

#define IN_F 4096
#define OUT_F 14336
#define BATCH 8
#define TN_TILES 896     // OUT_F/16
#define KSLICES 8
#define ITERS 16         // MFMA K-steps per kslice (each = 2 k-tiles = K:32)
#define RS128 0.08838834764831845f  // 1/sqrt(128)

typedef __attribute__((ext_vector_type(4))) float f32x4;
typedef __attribute__((ext_vector_type(8))) _Float16 f16x8;
typedef __attribute__((ext_vector_type(2))) unsigned short u16x2;

// Module-scope scratch -> zero dependence on ws_size.
__device__ _Float16 g_xh[BATCH * IN_F];   // rotated input, f16
__device__ float g_y[BATCH * OUT_F];      // f32 accumulator for y

// ---------------------------------------------------------------------------
// Input rotation: g_xh = FWHT128(x * suh) / sqrt(128), f16 [8][4096].
// Self-probes the float transport format (fp16-upcast-to-f32 has mantissa
// bits 12..0 == 0 on every word; raw-16-bit transport essentially never).
// Also zeroes g_y (each of the 256 blocks clears 448 floats).
__global__ void k_rot_in(const void* __restrict__ xp,
                         const void* __restrict__ suhp) {
  const int b = blockIdx.x;          // 0..255 = 8 rows * 32 blocks
  const int row = b >> 5, blk = b & 31;
  const int lane = threadIdx.x;      // 0..63
  const uint32_t ffmt =
      __any((((const uint32_t*)xp)[lane] & 0x1FFFu) != 0) ? 0u : 1u;
  {
    int base = b * 448;
    #pragma unroll
    for (int k = 0; k < 7; ++k) g_y[base + k * 64 + lane] = 0.f;
  }
  const int i0 = blk * 128 + lane;
  float x0, x1, s0, s1;
  if (ffmt) {
    const float* x = (const float*)xp;
    const float* sh = (const float*)suhp;
    x0 = x[row * IN_F + i0];      x1 = x[row * IN_F + i0 + 64];
    s0 = sh[i0];                  s1 = sh[i0 + 64];
  } else {
    const __hip_bfloat16* x = (const __hip_bfloat16*)xp;
    const __hip_bfloat16* sh = (const __hip_bfloat16*)suhp;
    x0 = __bfloat162float(x[row * IN_F + i0]);
    x1 = __bfloat162float(x[row * IN_F + i0 + 64]);
    s0 = __bfloat162float(sh[i0]);
    s1 = __bfloat162float(sh[i0 + 64]);
  }
  float v0 = x0 * s0 * RS128;
  float v1 = x1 * s1 * RS128;
  { float a = v0 + v1, s = v0 - v1; v0 = a; v1 = s; }  // distance-64 stage
  #pragma unroll
  for (int d = 32; d >= 1; d >>= 1) {
    float w0 = __shfl_xor(v0, d);
    float w1 = __shfl_xor(v1, d);
    if (lane & d) { v0 = w0 - v0; v1 = w1 - v1; }
    else          { v0 = v0 + w0; v1 = v1 + w1; }
  }
  g_xh[row * IN_F + i0]      = (_Float16)v0;
  g_xh[row * IN_F + i0 + 64] = (_Float16)v1;
}

// ---------------------------------------------------------------------------
// Main kernel. Grid (224, 8): wave wv of block bx owns tile-column
// tn = bx*4+wv for kslice ks (32 k-tiles).
//   PROLOGUE: lane l bulk-loads half a tile (tile l>>1, half l&1; 48 B =
//   3 dwordx4), builds comb windows c[w] = u[w]<<16 | u[w+1], writes them to
//   a wave-private LDS slice (6 ds_write_b128). Wave-private + same-wave DS
//   ordering => NO barriers anywhere.
//   K-LOOP (software-pipelined): prefetch iter it+1's 8 comb words (4
//   ds_read2_b32) and A-fragment (1 global dwordx4, L1-hot) into registers
//   while decoding iter it. Decode is the QTIP 3INST LCG with the hi-16 half
//   done in packed u16 math (bit-identical: z>>16 = ((t>>16)+st*1361) mod
//   2^16 where t = st*31858 + C, z = t + (st*1361 << 16)).
// B-frag: lane holds B[k=(lane>>4)*8+j][n=lane&15]. Weight (u=k&15, c=n&15)
// has bit offset 48u+3c -> word w0+3j, shift 16-((3c)&15), w0=3*r0+((3c)>>4).
__global__ __launch_bounds__(256) void k_main(const uint32_t* __restrict__ tr) {
  __shared__ uint32_t cwin[4][32][48];  // [wave][tile (=2*it+par)][comb words]
  const int t = threadIdx.x;
  const int lane = t & 63;
  const int wv = t >> 6;
  const int tn = blockIdx.x * 4 + wv;
  const int ks = blockIdx.y;
  // self-probe trellis transport: raw u16 (high halves nonzero) vs 1/int32
  const uint32_t fmt = __any((tr[lane] >> 16) != 0) ? 1u : 0u;

  // ---- prologue ----
  const int tile = lane >> 1;   // 0..31
  const int h = lane & 1;       // which 24-u16 half of the tile
  uint32_t d[12];
  if (fmt) {
    const uint4* gp = (const uint4*)(tr +
        ((long)(ks * 32 + tile) * TN_TILES + tn) * 24 + h * 12);
    uint4 a0 = gp[0], a1 = gp[1], a2 = gp[2];
    d[0] = a0.x; d[1] = a0.y; d[2]  = a0.z; d[3]  = a0.w;
    d[4] = a1.x; d[5] = a1.y; d[6]  = a1.z; d[7]  = a1.w;
    d[8] = a2.x; d[9] = a2.y; d[10] = a2.z; d[11] = a2.w;
  } else {
    const uint4* gp = (const uint4*)(tr +
        ((long)(ks * 32 + tile) * TN_TILES + tn) * 48 + h * 24);
    uint4 b0 = gp[0], b1 = gp[1], b2 = gp[2];
    uint4 b3 = gp[3], b4 = gp[4], b5 = gp[5];
    d[0]  = __builtin_amdgcn_perm(b0.y, b0.x, 0x05040100u);
    d[1]  = __builtin_amdgcn_perm(b0.w, b0.z, 0x05040100u);
    d[2]  = __builtin_amdgcn_perm(b1.y, b1.x, 0x05040100u);
    d[3]  = __builtin_amdgcn_perm(b1.w, b1.z, 0x05040100u);
    d[4]  = __builtin_amdgcn_perm(b2.y, b2.x, 0x05040100u);
    d[5]  = __builtin_amdgcn_perm(b2.w, b2.z, 0x05040100u);
    d[6]  = __builtin_amdgcn_perm(b3.y, b3.x, 0x05040100u);
    d[7]  = __builtin_amdgcn_perm(b3.w, b3.z, 0x05040100u);
    d[8]  = __builtin_amdgcn_perm(b4.y, b4.x, 0x05040100u);
    d[9]  = __builtin_amdgcn_perm(b4.w, b4.z, 0x05040100u);
    d[10] = __builtin_amdgcn_perm(b5.y, b5.x, 0x05040100u);
    d[11] = __builtin_amdgcn_perm(b5.w, b5.z, 0x05040100u);
  }
  uint32_t dnext = __shfl(d[0], lane ^ 1, 64);  // partner supplies u[24]/wrap
  uint32_t c[24];
  #pragma unroll
  for (int m = 0; m < 12; ++m) {
    uint32_t nx = (m < 11) ? d[m + 1] : dnext;
    c[2 * m]     = (d[m] >> 16) | (d[m] << 16);
    c[2 * m + 1] = __builtin_amdgcn_perm(d[m], nx, 0x07060100u);
  }
  {
    uint32_t* wp = &cwin[wv][tile][h * 24];
    #pragma unroll
    for (int k = 0; k < 6; ++k)
      *(uint4*)(wp + 4 * k) = *(const uint4*)(c + 4 * k);
  }
  // no barrier: each wave reads only its own slice (same-wave DS in-order)

  // ---- K-loop ----
  const int q = lane >> 4;           // k-octet 0..3
  const int cc = lane & 15;          // column within tile
  const int par = q >> 1;            // which tile of the K=32 pair
  const int w0 = 3 * ((q & 1) << 3) + ((3 * cc) >> 4);
  const uint32_t shr = 16u - (uint32_t)((3 * cc) & 15);  // 1..16
  const uint32_t* myc = &cwin[wv][par][w0];

  auto lds_fetch = [&](int it, uint32_t* dst) {
    const uint32_t* cb = myc + it * 96;   // 2 tiles per iter
    #pragma unroll
    for (int g = 0; g < 4; ++g) {         // pairs -> ds_read2_b32
      dst[2 * g]     = cb[6 * g];
      dst[2 * g + 1] = cb[6 * g + 3];
    }
  };
  auto a_fetch = [&](int it) -> f16x8 {
    f16x8 a = {0, 0, 0, 0, 0, 0, 0, 0};
    if (cc < 8)
      a = *(const f16x8*)(g_xh + cc * IN_F + ks * 512 + it * 32 + q * 8);
    return a;
  };

  f32x4 acc = {0.f, 0.f, 0.f, 0.f};
  uint32_t cwA[8];
  lds_fetch(0, cwA);
  f16x8 aA = a_fetch(0);

  #pragma unroll 4
  for (int it = 0; it < ITERS; ++it) {
    uint32_t cwN[8] = {0, 0, 0, 0, 0, 0, 0, 0};
    f16x8 aN = {0, 0, 0, 0, 0, 0, 0, 0};
    if (it + 1 < ITERS) {
      lds_fetch(it + 1, cwN);
      aN = a_fetch(it + 1);
    }

    union { __half2 h2[4]; f16x8 v; } bfrag;
    #pragma unroll
    for (int g = 0; g < 4; ++g) {
      uint32_t c0 = cwA[2 * g], c1 = cwA[2 * g + 1];
      uint32_t st0 = (c0 >> shr) & 0xFFFFu;   // v_bfe
      uint32_t st1 = (c1 >> shr) & 0xFFFFu;
      uint32_t t0 = __umul24(st0, 31858u) + 64248484u;  // v_mad_u32_u24
      uint32_t t1 = __umul24(st1, 31858u) + 64248484u;
      union { uint32_t u; u16x2 v; } sp, pm, th;
      sp.u = __builtin_amdgcn_perm(st1, st0, 0x05040100u); // (st0, st1) packed
      pm.v = sp.v * (u16x2){1361, 1361};                   // v_pk_mul_lo_u16
      th.u = __builtin_amdgcn_perm(t1, t0, 0x07060302u);   // (t0>>16, t1>>16)
      th.v = th.v + pm.v;                                  // v_pk_add_u16
      uint32_t hi = th.u & 0x8FFF8FFFu;
      uint32_t lo = __builtin_amdgcn_perm(t1, t0, 0x05040100u) & 0x8FFF8FFFu;
      __half2 ha = *(__half2*)&lo;
      __half2 hb = *(__half2*)&hi;
      bfrag.h2[g] = __hadd2(ha, hb);   // two finished weights, packed f16
    }

    acc = __builtin_amdgcn_mfma_f32_16x16x32_f16(aA, bfrag.v, acc, 0, 0, 0);

    #pragma unroll
    for (int g = 0; g < 8; ++g) cwA[g] = cwN[g];
    aA = aN;
  }

  // C layout: col = lane&15, row = (lane>>4)*4 + reg; rows 0..7 are real.
  if (q < 2) {
    const int n = tn * 16 + cc;
    #pragma unroll
    for (int rg = 0; rg < 4; ++rg)
      atomicAdd(&g_y[(q * 4 + rg) * OUT_F + n], acc[rg]);
  }
}

// ---------------------------------------------------------------------------
// Output rotation: out = FWHT128(g_y)/sqrt(128)*svh + bias.
// Self-probes the float transport format from x (same rule as k_rot_in).
__global__ void k_rot_out(const void* __restrict__ xp,
                          const void* __restrict__ svhp,
                          const void* __restrict__ biasp,
                          void* __restrict__ outp) {
  const int nblk = blockIdx.x;   // 0..111
  const int row = blockIdx.y;    // 0..7
  const int lane = threadIdx.x;  // 0..63
  const uint32_t ffmt =
      __any((((const uint32_t*)xp)[lane] & 0x1FFFu) != 0) ? 0u : 1u;
  const int n0 = nblk * 128 + lane;
  float v0 = g_y[row * OUT_F + n0] * RS128;
  float v1 = g_y[row * OUT_F + n0 + 64] * RS128;
  { float a = v0 + v1, s = v0 - v1; v0 = a; v1 = s; }
  #pragma unroll
  for (int d = 32; d >= 1; d >>= 1) {
    float w0 = __shfl_xor(v0, d);
    float w1 = __shfl_xor(v1, d);
    if (lane & d) { v0 = w0 - v0; v1 = w1 - v1; }
    else          { v0 = v0 + w0; v1 = v1 + w1; }
  }
  if (ffmt) {
    const float* svh = (const float*)svhp;
    const float* bias = (const float*)biasp;
    float* out = (float*)outp;
    out[(long)row * OUT_F + n0]      = v0 * svh[n0] + bias[n0];
    out[(long)row * OUT_F + n0 + 64] = v1 * svh[n0 + 64] + bias[n0 + 64];
  } else {
    const __hip_bfloat16* svh = (const __hip_bfloat16*)svhp;
    const __hip_bfloat16* bias = (const __hip_bfloat16*)biasp;
    __hip_bfloat16* out = (__hip_bfloat16*)outp;
    out[(long)row * OUT_F + n0] = __float2bfloat16(
        v0 * __bfloat162float(svh[n0]) + __bfloat162float(bias[n0]));
    out[(long)row * OUT_F + n0 + 64] = __float2bfloat16(
        v1 * __bfloat162float(svh[n0 + 64]) + __bfloat162float(bias[n0 + 64]));
  }
}

// ---------------------------------------------------------------------------
extern "C" void kernel_launch(void* const* d_in, const int* in_sizes, int n_in,
                              void* d_out, int out_size, void* d_ws,
                              size_t ws_size, hipStream_t stream) {
  const void*     x    = d_in[0];
  const uint32_t* tr   = (const uint32_t*)d_in[1];
  const void*     suh  = d_in[2];
  const void*     svh  = d_in[3];
  const void*     bias = d_in[4];

  k_rot_in<<<256, 64, 0, stream>>>(x, suh);
  k_main<<<dim3(TN_TILES / 4, KSLICES), 256, 0, stream>>>(tr);
  k_rot_out<<<dim3(OUT_F / 128, BATCH), 64, 0, stream>>>(x, svh, bias, d_out);
}

// Round 7
// 103.918 us; speedup vs baseline: 1.2274x; 1.0095x over previous
//
#include <hip/hip_runtime.h>
#include <hip/hip_fp16.h>
#include <hip/hip_bf16.h>
#include <stdint.h>

// EXL3 linear: out = Had128( Had128(x*suh) @ dequant(trellis) ) * svh + bias
// B=8, K=4096, N=14336. Tiles are 16x16, 48 uint16 words per tile.

#define IN_F 4096
#define OUT_F 14336
#define BATCH 8
#define TN_TILES 896     // OUT_F/16
#define KSLICES 8
#define ITERS 16         // MFMA K-steps per kslice (each = 2 k-tiles = K:32)
#define RS128 0.08838834764831845f  // 1/sqrt(128)

typedef __attribute__((ext_vector_type(4))) float f32x4;
typedef __attribute__((ext_vector_type(8))) _Float16 f16x8;
typedef __attribute__((ext_vector_type(2))) unsigned short u16x2;

// Module-scope scratch -> zero dependence on ws_size.
__device__ _Float16 g_xh[BATCH * IN_F];              // rotated input, f16
__device__ float g_part[KSLICES * BATCH * OUT_F];    // per-kslice partials

// ---------------------------------------------------------------------------
// Input rotation: g_xh = FWHT128(x * suh) / sqrt(128), f16 [8][4096].
// Self-probes the float transport format (fp16-upcast-to-f32 has mantissa
// bits 12..0 == 0 on every word; raw-16-bit transport essentially never).
__global__ void k_rot_in(const void* __restrict__ xp,
                         const void* __restrict__ suhp) {
  const int b = blockIdx.x;          // 0..255 = 8 rows * 32 blocks
  const int row = b >> 5, blk = b & 31;
  const int lane = threadIdx.x;      // 0..63
  const uint32_t ffmt =
      __any((((const uint32_t*)xp)[lane] & 0x1FFFu) != 0) ? 0u : 1u;
  const int i0 = blk * 128 + lane;
  float x0, x1, s0, s1;
  if (ffmt) {
    const float* x = (const float*)xp;
    const float* sh = (const float*)suhp;
    x0 = x[row * IN_F + i0];      x1 = x[row * IN_F + i0 + 64];
    s0 = sh[i0];                  s1 = sh[i0 + 64];
  } else {
    const __hip_bfloat16* x = (const __hip_bfloat16*)xp;
    const __hip_bfloat16* sh = (const __hip_bfloat16*)suhp;
    x0 = __bfloat162float(x[row * IN_F + i0]);
    x1 = __bfloat162float(x[row * IN_F + i0 + 64]);
    s0 = __bfloat162float(sh[i0]);
    s1 = __bfloat162float(sh[i0 + 64]);
  }
  float v0 = x0 * s0 * RS128;
  float v1 = x1 * s1 * RS128;
  { float a = v0 + v1, s = v0 - v1; v0 = a; v1 = s; }  // distance-64 stage
  #pragma unroll
  for (int d = 32; d >= 1; d >>= 1) {
    float w0 = __shfl_xor(v0, d);
    float w1 = __shfl_xor(v1, d);
    if (lane & d) { v0 = w0 - v0; v1 = w1 - v1; }
    else          { v0 = v0 + w0; v1 = v1 + w1; }
  }
  g_xh[row * IN_F + i0]      = (_Float16)v0;
  g_xh[row * IN_F + i0 + 64] = (_Float16)v1;
}

// ---------------------------------------------------------------------------
// Main kernel. Grid (224, 8): wave wv of block bx owns tile-column
// tn = bx*4+wv for kslice ks (32 k-tiles).
//   PROLOGUE: lane l bulk-loads half a tile (tile l>>1, half l&1; 48 B =
//   3 dwordx4), builds comb windows c[w] = u[w]<<16 | u[w+1], writes them to
//   a wave-private LDS slice (6 ds_write_b128). Wave-private + same-wave DS
//   ordering => NO barriers anywhere.
//   K-LOOP (software-pipelined): prefetch iter it+1's 8 comb words (4
//   ds_read2_b32) and A-fragment (1 global dwordx4, L1/L2-hot) into registers
//   while decoding iter it. Decode is the QTIP 3INST LCG with the hi-16 half
//   in packed u16 math (bit-identical: z>>16 = ((t>>16)+st*1361) mod 2^16
//   where t = st*31858 + C, z = t + (st*1361 << 16)).
//   EPILOGUE: plain coalesced stores to g_part[ks] (no atomics).
// B-frag: lane holds B[k=(lane>>4)*8+j][n=lane&15]. Weight (u=k&15, c=n&15)
// has bit offset 48u+3c -> word w0+3j, shift 16-((3c)&15), w0=3*r0+((3c)>>4).
__global__ __launch_bounds__(256) void k_main(const uint32_t* __restrict__ tr) {
  __shared__ uint32_t cwin[4][32][48];  // [wave][tile (=2*it+par)][comb words]
  const int t = threadIdx.x;
  const int lane = t & 63;
  const int wv = t >> 6;
  const int tn = blockIdx.x * 4 + wv;
  const int ks = blockIdx.y;
  // self-probe trellis transport: raw u16 (high halves nonzero) vs 1/int32
  const uint32_t fmt = __any((tr[lane] >> 16) != 0) ? 1u : 0u;

  // ---- prologue ----
  const int tile = lane >> 1;   // 0..31
  const int h = lane & 1;       // which 24-u16 half of the tile
  uint32_t d[12];
  if (fmt) {
    const uint4* gp = (const uint4*)(tr +
        ((long)(ks * 32 + tile) * TN_TILES + tn) * 24 + h * 12);
    uint4 a0 = gp[0], a1 = gp[1], a2 = gp[2];
    d[0] = a0.x; d[1] = a0.y; d[2]  = a0.z; d[3]  = a0.w;
    d[4] = a1.x; d[5] = a1.y; d[6]  = a1.z; d[7]  = a1.w;
    d[8] = a2.x; d[9] = a2.y; d[10] = a2.z; d[11] = a2.w;
  } else {
    const uint4* gp = (const uint4*)(tr +
        ((long)(ks * 32 + tile) * TN_TILES + tn) * 48 + h * 24);
    uint4 b0 = gp[0], b1 = gp[1], b2 = gp[2];
    uint4 b3 = gp[3], b4 = gp[4], b5 = gp[5];
    d[0]  = __builtin_amdgcn_perm(b0.y, b0.x, 0x05040100u);
    d[1]  = __builtin_amdgcn_perm(b0.w, b0.z, 0x05040100u);
    d[2]  = __builtin_amdgcn_perm(b1.y, b1.x, 0x05040100u);
    d[3]  = __builtin_amdgcn_perm(b1.w, b1.z, 0x05040100u);
    d[4]  = __builtin_amdgcn_perm(b2.y, b2.x, 0x05040100u);
    d[5]  = __builtin_amdgcn_perm(b2.w, b2.z, 0x05040100u);
    d[6]  = __builtin_amdgcn_perm(b3.y, b3.x, 0x05040100u);
    d[7]  = __builtin_amdgcn_perm(b3.w, b3.z, 0x05040100u);
    d[8]  = __builtin_amdgcn_perm(b4.y, b4.x, 0x05040100u);
    d[9]  = __builtin_amdgcn_perm(b4.w, b4.z, 0x05040100u);
    d[10] = __builtin_amdgcn_perm(b5.y, b5.x, 0x05040100u);
    d[11] = __builtin_amdgcn_perm(b5.w, b5.z, 0x05040100u);
  }
  uint32_t dnext = __shfl(d[0], lane ^ 1, 64);  // partner supplies u[24]/wrap
  uint32_t c[24];
  #pragma unroll
  for (int m = 0; m < 12; ++m) {
    uint32_t nx = (m < 11) ? d[m + 1] : dnext;
    c[2 * m]     = (d[m] >> 16) | (d[m] << 16);
    c[2 * m + 1] = __builtin_amdgcn_perm(d[m], nx, 0x07060100u);
  }
  {
    uint32_t* wp = &cwin[wv][tile][h * 24];
    #pragma unroll
    for (int k = 0; k < 6; ++k)
      *(uint4*)(wp + 4 * k) = *(const uint4*)(c + 4 * k);
  }
  // no barrier: each wave reads only its own slice (same-wave DS in-order)

  // ---- K-loop ----
  const int q = lane >> 4;           // k-octet 0..3
  const int cc = lane & 15;          // column within tile
  const int par = q >> 1;            // which tile of the K=32 pair
  const int w0 = 3 * ((q & 1) << 3) + ((3 * cc) >> 4);
  const uint32_t shr = 16u - (uint32_t)((3 * cc) & 15);  // 1..16
  const uint32_t* myc = &cwin[wv][par][w0];

  auto lds_fetch = [&](int it, uint32_t* dst) {
    const uint32_t* cb = myc + it * 96;   // 2 tiles per iter
    #pragma unroll
    for (int g = 0; g < 4; ++g) {         // pairs -> ds_read2_b32
      dst[2 * g]     = cb[6 * g];
      dst[2 * g + 1] = cb[6 * g + 3];
    }
  };
  auto a_fetch = [&](int it) -> f16x8 {
    f16x8 a = {0, 0, 0, 0, 0, 0, 0, 0};
    if (cc < 8)
      a = *(const f16x8*)(g_xh + cc * IN_F + ks * 512 + it * 32 + q * 8);
    return a;
  };

  f32x4 acc = {0.f, 0.f, 0.f, 0.f};
  uint32_t cwA[8];
  lds_fetch(0, cwA);
  f16x8 aA = a_fetch(0);

  #pragma unroll 4
  for (int it = 0; it < ITERS; ++it) {
    uint32_t cwN[8] = {0, 0, 0, 0, 0, 0, 0, 0};
    f16x8 aN = {0, 0, 0, 0, 0, 0, 0, 0};
    if (it + 1 < ITERS) {
      lds_fetch(it + 1, cwN);
      aN = a_fetch(it + 1);
    }

    union { __half2 h2[4]; f16x8 v; } bfrag;
    #pragma unroll
    for (int g = 0; g < 4; ++g) {
      uint32_t c0 = cwA[2 * g], c1 = cwA[2 * g + 1];
      uint32_t st0 = (c0 >> shr) & 0xFFFFu;   // v_bfe
      uint32_t st1 = (c1 >> shr) & 0xFFFFu;
      uint32_t t0 = __umul24(st0, 31858u) + 64248484u;  // v_mad_u32_u24
      uint32_t t1 = __umul24(st1, 31858u) + 64248484u;
      union { uint32_t u; u16x2 v; } sp, pm, th;
      sp.u = __builtin_amdgcn_perm(st1, st0, 0x05040100u); // (st0, st1) packed
      pm.v = sp.v * (u16x2){1361, 1361};                   // v_pk_mul_lo_u16
      th.u = __builtin_amdgcn_perm(t1, t0, 0x07060302u);   // (t0>>16, t1>>16)
      th.v = th.v + pm.v;                                  // v_pk_add_u16
      uint32_t hi = th.u & 0x8FFF8FFFu;
      uint32_t lo = __builtin_amdgcn_perm(t1, t0, 0x05040100u) & 0x8FFF8FFFu;
      __half2 ha = *(__half2*)&lo;
      __half2 hb = *(__half2*)&hi;
      bfrag.h2[g] = __hadd2(ha, hb);   // two finished weights, packed f16
    }

    acc = __builtin_amdgcn_mfma_f32_16x16x32_f16(aA, bfrag.v, acc, 0, 0, 0);

    #pragma unroll
    for (int g = 0; g < 8; ++g) cwA[g] = cwN[g];
    aA = aN;
  }

  // C layout: col = lane&15, row = (lane>>4)*4 + reg; rows 0..7 are real.
  // Plain coalesced stores to this kslice's partial slice (no atomics).
  if (q < 2) {
    const int n = tn * 16 + cc;
    #pragma unroll
    for (int rg = 0; rg < 4; ++rg)
      g_part[((ks * BATCH) + q * 4 + rg) * OUT_F + n] = acc[rg];
  }
}

// ---------------------------------------------------------------------------
// Output rotation: y = sum_ks g_part; out = FWHT128(y)/sqrt(128)*svh + bias.
// Self-probes the float transport format from x (same rule as k_rot_in).
__global__ void k_rot_out(const void* __restrict__ xp,
                          const void* __restrict__ svhp,
                          const void* __restrict__ biasp,
                          void* __restrict__ outp) {
  const int nblk = blockIdx.x;   // 0..111
  const int row = blockIdx.y;    // 0..7
  const int lane = threadIdx.x;  // 0..63
  const uint32_t ffmt =
      __any((((const uint32_t*)xp)[lane] & 0x1FFFu) != 0) ? 0u : 1u;
  const int n0 = nblk * 128 + lane;
  float v0 = 0.f, v1 = 0.f;
  #pragma unroll
  for (int s = 0; s < KSLICES; ++s) {
    v0 += g_part[(s * BATCH + row) * OUT_F + n0];
    v1 += g_part[(s * BATCH + row) * OUT_F + n0 + 64];
  }
  v0 *= RS128; v1 *= RS128;
  { float a = v0 + v1, s = v0 - v1; v0 = a; v1 = s; }
  #pragma unroll
  for (int d = 32; d >= 1; d >>= 1) {
    float w0 = __shfl_xor(v0, d);
    float w1 = __shfl_xor(v1, d);
    if (lane & d) { v0 = w0 - v0; v1 = w1 - v1; }
    else          { v0 = v0 + w0; v1 = v1 + w1; }
  }
  if (ffmt) {
    const float* svh = (const float*)svhp;
    const float* bias = (const float*)biasp;
    float* out = (float*)outp;
    out[(long)row * OUT_F + n0]      = v0 * svh[n0] + bias[n0];
    out[(long)row * OUT_F + n0 + 64] = v1 * svh[n0 + 64] + bias[n0 + 64];
  } else {
    const __hip_bfloat16* svh = (const __hip_bfloat16*)svhp;
    const __hip_bfloat16* bias = (const __hip_bfloat16*)biasp;
    __hip_bfloat16* out = (__hip_bfloat16*)outp;
    out[(long)row * OUT_F + n0] = __float2bfloat16(
        v0 * __bfloat162float(svh[n0]) + __bfloat162float(bias[n0]));
    out[(long)row * OUT_F + n0 + 64] = __float2bfloat16(
        v1 * __bfloat162float(svh[n0 + 64]) + __bfloat162float(bias[n0 + 64]));
  }
}

// ---------------------------------------------------------------------------
extern "C" void kernel_launch(void* const* d_in, const int* in_sizes, int n_in,
                              void* d_out, int out_size, void* d_ws,
                              size_t ws_size, hipStream_t stream) {
  const void*     x    = d_in[0];
  const uint32_t* tr   = (const uint32_t*)d_in[1];
  const void*     suh  = d_in[2];
  const void*     svh  = d_in[3];
  const void*     bias = d_in[4];

  k_rot_in<<<256, 64, 0, stream>>>(x, suh);
  k_main<<<dim3(TN_TILES / 4, KSLICES), 256, 0, stream>>>(tr);
  k_rot_out<<<dim3(OUT_F / 128, BATCH), 64, 0, stream>>>(x, svh, bias, d_out);
}